// Round 9
// baseline (102.005 us; speedup 1.0000x reference)
//
#include <hip/hip_runtime.h>
#include <math.h>

#define B_TOT 16384
#define H     128
#define NC    10
#define NATT  3
#define HBS   136     // bf16 LDS row stride in ushorts (272B, 16B-aligned)
#define EPS   1e-5f

typedef __attribute__((ext_vector_type(8))) short bf16x8;
typedef __attribute__((ext_vector_type(4))) float f32x4;

__device__ __forceinline__ ushort f2bf(float f) {
    union { float f; unsigned u; } v; v.f = f;
    unsigned r = v.u + 0x7fffu + ((v.u >> 16) & 1u);   // RNE
    return (ushort)(r >> 16);
}

// tanh(a) = 1 - 2/(e^{2a}+1); saturates correctly for |a| large
__device__ __forceinline__ float fast_tanh(float a) {
    float t = __expf(2.f * a);
    return 1.f - 2.f * __builtin_amdgcn_rcpf(t + 1.f);
}

// butterfly all-reduce over the 4 q-groups (lane bits 4,5)
__device__ __forceinline__ float redq(float v) {
    v += __shfl_xor(v, 16);
    v += __shfl_xor(v, 32);
    return v;
}

// ---- prep: wt[mat][n][k]; mat0=W_in^T, mat1..3=W_att^T, mat4=W_c^T padded to 16 rows ----
extern "C" __global__ __launch_bounds__(256)
void prep_weights(const float* __restrict__ W_in,
                  const float* __restrict__ W_att,
                  const float* __restrict__ W_c,
                  ushort* __restrict__ wt)
{
    int i = blockIdx.x * 256 + threadIdx.x;
    if (i < 65536) {
        int mat = i >> 14, idx = i & 16383;
        int k = idx >> 7, n = idx & 127;
        float v = (mat == 0) ? W_in[idx] : W_att[(mat - 1) * 16384 + idx];
        wt[mat * 16384 + n * H + k] = f2bf(v);
    } else if (i < 65536 + 2048) {
        int idx = i - 65536;
        int n = idx >> 7, k = idx & 127;
        float v = (n < NC) ? W_c[k * NC + n] : 0.f;
        wt[65536 + n * H + k] = f2bf(v);
    }
}

// One wave (64 threads) per block; each wave owns 16 batch rows END-TO-END.
// Transposed GEMMs C[n][b]: lane (s,q) holds batch s, n = 16t+4q+r across 8 n-tiles.
// All H-reductions are wave-local (in-lane 32-sum + shfl_xor butterfly over q).
// No cross-wave exchange, no multi-wave barriers.
extern "C" __global__ __launch_bounds__(64)
void simple_attention_kernel(const float* __restrict__ x,
                             const float* __restrict__ b_in,
                             const float* __restrict__ b_att,
                             const float* __restrict__ gamma,
                             const float* __restrict__ beta,
                             const float* __restrict__ b_c,
                             const ushort* __restrict__ wt,
                             float* __restrict__ out)
{
    __shared__ __align__(16) ushort ab[16 * HBS];   // bf16 h tile [batch][n], 1 wave

    const int lane = threadIdx.x;       // 0..63
    const int s    = lane & 15;         // batch index (C column)
    const int q    = lane >> 4;
    const size_t base = (size_t)blockIdx.x * 16;

    float h[32];   // h[4t+r]: batch s, n = 16t+4q+r (fp32 across layers)
    float u[32];

    // ---- in_proj: B-frags straight from global x; 8 n-tiles ----
    {
        bf16x8 bfr[4];
        #pragma unroll
        for (int ks = 0; ks < 4; ++ks) {
            const float* xp = x + (base + s) * H + ks * 32 + q * 8;
            float4 v0 = *(const float4*)xp;
            float4 v1 = *(const float4*)(xp + 4);
            bf16x8 a;
            a[0] = f2bf(v0.x); a[1] = f2bf(v0.y); a[2] = f2bf(v0.z); a[3] = f2bf(v0.w);
            a[4] = f2bf(v1.x); a[5] = f2bf(v1.y); a[6] = f2bf(v1.z); a[7] = f2bf(v1.w);
            bfr[ks] = a;
        }
        #pragma unroll
        for (int t = 0; t < 8; ++t) {
            f32x4 acc = (f32x4){0.f, 0.f, 0.f, 0.f};
            #pragma unroll
            for (int ks = 0; ks < 4; ++ks) {
                bf16x8 a = *(const bf16x8*)&wt[(16 * t + s) * H + ks * 32 + q * 8];
                acc = __builtin_amdgcn_mfma_f32_16x16x32_bf16(a, bfr[ks], acc, 0, 0, 0);
            }
            float4 bi = *(const float4*)&b_in[16 * t + 4 * q];
            float h0 = acc[0] + bi.x, h1 = acc[1] + bi.y;
            float h2 = acc[2] + bi.z, h3 = acc[3] + bi.w;
            h[4 * t + 0] = h0; h[4 * t + 1] = h1;
            h[4 * t + 2] = h2; h[4 * t + 3] = h3;
            uint lo = (uint)f2bf(h0) | ((uint)f2bf(h1) << 16);
            uint hi = (uint)f2bf(h2) | ((uint)f2bf(h3) << 16);
            *(uint2*)&ab[s * HBS + 16 * t + 4 * q] = make_uint2(lo, hi);
        }
    }
    __syncthreads();   // single-wave barrier: orders LDS writes before cross-lane reads

    // degree-4 Chebyshev-truncated minimax of e^v on [-1,1]
    const float cm[5] = {1.00004478f, 0.99730768f, 0.49919676f, 0.17734736f, 0.04379392f};

    #pragma unroll 1
    for (int layer = 0; layer < NATT; ++layer) {
        const ushort* WT = wt + (size_t)(1 + layer) * 16384;

        // ---- B-frags: h redistribution via LDS (only LDS use per layer) ----
        bf16x8 bfr[4];
        #pragma unroll
        for (int ks = 0; ks < 4; ++ks)
            bfr[ks] = *(const bf16x8*)&ab[s * HBS + ks * 32 + q * 8];

        // ---- GEMM + tanh + moment accumulation, 8 sequential n-tiles ----
        float m0 = 0, m1 = 0, m2 = 0, m3 = 0, m4 = 0;
        float t1 = 0, t2 = 0, t3 = 0, t4 = 0;
        #pragma unroll
        for (int t = 0; t < 8; ++t) {
            f32x4 acc = (f32x4){0.f, 0.f, 0.f, 0.f};
            #pragma unroll
            for (int ks = 0; ks < 4; ++ks) {
                bf16x8 a = *(const bf16x8*)&WT[(16 * t + s) * H + ks * 32 + q * 8];
                acc = __builtin_amdgcn_mfma_f32_16x16x32_bf16(a, bfr[ks], acc, 0, 0, 0);
            }
            float4 ba = *(const float4*)&b_att[layer * H + 16 * t + 4 * q];
            float bav[4] = {ba.x, ba.y, ba.z, ba.w};
            #pragma unroll
            for (int r = 0; r < 4; ++r) {
                float uu = fast_tanh(acc[r] + bav[r]);
                u[4 * t + r] = uu;
                float hh = h[4 * t + r];
                m0 += hh;
                float p = uu;
                m1 += p * hh; t1 += p;
                p *= uu; m2 += p * hh; t2 += p;
                p *= uu; m3 += p * hh; t3 += p;
                p *= uu; m4 += p * hh; t4 += p;
            }
        }

        // ---- wave-local completion of the 128-sum: butterfly over q ----
        m0 = redq(m0); m1 = redq(m1); m2 = redq(m2); m3 = redq(m3); m4 = redq(m4);
        t1 = redq(t1); t2 = redq(t2); t3 = redq(t3); t4 = redq(t4);
        float S0 = m0 * cm[0], S1 = m1 * cm[1], S2 = m2 * cm[2];
        float S3 = m3 * cm[3], S4 = m4 * cm[4];
        float T1 = t1 * cm[1], T2 = t2 * cm[2], T3 = t3 * cm[3], T4 = t4 * cm[4];

        // ---- Horner + residual + LN partials over the lane's 32 elements ----
        float ls = 0.f, lq2 = 0.f;
        #pragma unroll
        for (int i = 0; i < 32; ++i) {
            float uu = u[i];
            float num = fmaf(fmaf(fmaf(fmaf(S4, uu, S3), uu, S2), uu, S1), uu, S0);
            float den = fmaf(fmaf(fmaf(fmaf(T4, uu, T3), uu, T2), uu, T1), uu,
                             128.f * 1.00004478f);   // c0 * T0
            float yy = h[i] + num * __builtin_amdgcn_rcpf(den);
            h[i] = yy;
            ls += yy; lq2 += yy * yy;
        }
        ls  = redq(ls);
        lq2 = redq(lq2);
        float mu  = ls * (1.f / H);
        float var = lq2 * (1.f / H) - mu * mu;
        float inv = rsqrtf(var + EPS);

        // ---- LN epilogue: normalize in regs + refresh bf16 tile ----
        #pragma unroll
        for (int t = 0; t < 8; ++t) {
            float4 g4  = *(const float4*)&gamma[layer * H + 16 * t + 4 * q];
            float4 be4 = *(const float4*)&beta [layer * H + 16 * t + 4 * q];
            float h0 = (h[4 * t + 0] - mu) * inv * g4.x + be4.x;
            float h1 = (h[4 * t + 1] - mu) * inv * g4.y + be4.y;
            float h2 = (h[4 * t + 2] - mu) * inv * g4.z + be4.z;
            float h3 = (h[4 * t + 3] - mu) * inv * g4.w + be4.w;
            h[4 * t + 0] = h0; h[4 * t + 1] = h1;
            h[4 * t + 2] = h2; h[4 * t + 3] = h3;
            uint lo = (uint)f2bf(h0) | ((uint)f2bf(h1) << 16);
            uint hi = (uint)f2bf(h2) | ((uint)f2bf(h3) << 16);
            *(uint2*)&ab[s * HBS + 16 * t + 4 * q] = make_uint2(lo, hi);
        }
        __syncthreads();   // single-wave: order writes before next layer's bfr reads
    }

    // ---- final proj: one n-tile (W_c^T padded to 16 rows); C[nc][b] ----
    {
        const ushort* WC = wt + 4 * 16384;
        bf16x8 bfr[4];
        #pragma unroll
        for (int ks = 0; ks < 4; ++ks)
            bfr[ks] = *(const bf16x8*)&ab[s * HBS + ks * 32 + q * 8];
        f32x4 acc = (f32x4){0.f, 0.f, 0.f, 0.f};
        #pragma unroll
        for (int ks = 0; ks < 4; ++ks) {
            bf16x8 a = *(const bf16x8*)&WC[s * H + ks * 32 + q * 8];
            acc = __builtin_amdgcn_mfma_f32_16x16x32_bf16(a, bfr[ks], acc, 0, 0, 0);
        }
        #pragma unroll
        for (int r = 0; r < 4; ++r) {
            int nc = 4 * q + r;
            if (nc < NC)
                out[(base + s) * NC + nc] = acc[r] + b_c[nc];
        }
    }
}

extern "C" void kernel_launch(void* const* d_in, const int* in_sizes, int n_in,
                              void* d_out, int out_size, void* d_ws, size_t ws_size,
                              hipStream_t stream) {
    const float* x     = (const float*)d_in[0];
    const float* W_in  = (const float*)d_in[1];
    const float* b_in  = (const float*)d_in[2];
    const float* W_att = (const float*)d_in[3];
    const float* b_att = (const float*)d_in[4];
    const float* gamma = (const float*)d_in[5];
    const float* beta  = (const float*)d_in[6];
    const float* W_c   = (const float*)d_in[7];
    const float* b_c   = (const float*)d_in[8];
    float* out  = (float*)d_out;
    ushort* wt  = (ushort*)d_ws;    // 5 mats: 4*16384 + 2048 ushorts = 136 KiB

    hipLaunchKernelGGL(prep_weights, dim3(264), dim3(256), 0, stream,
                       W_in, W_att, W_c, wt);
    hipLaunchKernelGGL(simple_attention_kernel, dim3(B_TOT / 16), dim3(64), 0, stream,
                       x, b_in, b_att, gamma, beta, b_c, wt, out);
}

// Round 10
// 98.747 us; speedup vs baseline: 1.0330x; 1.0330x over previous
//
#include <hip/hip_runtime.h>
#include <math.h>

#define B_TOT 16384
#define H     128
#define NC    10
#define NATT  3
#define TRH   16      // batch rows per tile; 2 tiles per block (pipelined)
#define HBS   136     // bf16 LDS row stride in ushorts (272B, 16B-aligned)
#define KT    5       // degree-4 minimax of exp on [-1,1]; max err ~5.9e-4
#define EPS   1e-5f
#define EXM_S 100     // exm stride per batch-row (floats): 8 copies x 12 + 4 pad
#define EXL_S 20      // exl stride per batch-row (floats): 8 copies x 2 + 4 pad

typedef __attribute__((ext_vector_type(8))) short bf16x8;
typedef __attribute__((ext_vector_type(4))) float f32x4;

__device__ __forceinline__ ushort f2bf(float f) {
    union { float f; unsigned u; } v; v.f = f;
    unsigned r = v.u + 0x7fffu + ((v.u >> 16) & 1u);   // RNE
    return (ushort)(r >> 16);
}

// tanh(a) = 1 - 2/(e^{2a}+1); saturates correctly for |a| large
__device__ __forceinline__ float fast_tanh(float a) {
    float t = __expf(2.f * a);
    return 1.f - 2.f * __builtin_amdgcn_rcpf(t + 1.f);
}

// butterfly all-reduce over the 4 q-groups (lane bits 4,5)
__device__ __forceinline__ float redq(float v) {
    v += __shfl_xor(v, 16);
    v += __shfl_xor(v, 32);
    return v;
}

// ---- prep: wt[mat][n][k]; mat0=W_in^T, mat1..3=W_att^T, mat4=W_c^T padded to 16 rows ----
extern "C" __global__ __launch_bounds__(256)
void prep_weights(const float* __restrict__ W_in,
                  const float* __restrict__ W_att,
                  const float* __restrict__ W_c,
                  ushort* __restrict__ wt)
{
    int i = blockIdx.x * 256 + threadIdx.x;
    if (i < 65536) {
        int mat = i >> 14, idx = i & 16383;
        int k = idx >> 7, n = idx & 127;
        float v = (mat == 0) ? W_in[idx] : W_att[(mat - 1) * 16384 + idx];
        wt[mat * 16384 + n * H + k] = f2bf(v);
    } else if (i < 65536 + 2048) {
        int idx = i - 65536;
        int n = idx >> 7, k = idx & 127;
        float v = (n < NC) ? W_c[k * NC + n] : 0.f;
        wt[65536 + n * H + k] = f2bf(v);
    }
}

extern "C" __global__ __launch_bounds__(512, 4)
void simple_attention_kernel(const float* __restrict__ x,
                             const float* __restrict__ b_in,
                             const float* __restrict__ b_att,
                             const float* __restrict__ gamma,
                             const float* __restrict__ beta,
                             const float* __restrict__ b_c,
                             const ushort* __restrict__ wt,
                             float* __restrict__ out)
{
    __shared__ __align__(16) ushort ab[2][TRH * HBS];    // bf16 h tiles [tile][batch][n]
    __shared__ __align__(16) float  exm[2][16 * EXM_S];  // moment exchange per tile
    __shared__ __align__(16) float  exl[2][16 * EXL_S];  // LN exchange per tile

    const int tid  = threadIdx.x;
    const int wv   = tid >> 6;          // wave 0..7 owns n-tile [16wv, 16wv+16)
    const int lane = tid & 63;
    const int s    = lane & 15;         // C-col: BATCH index (within tile)
    const int q    = lane >> 4;
    const int nq   = 16 * wv + 4 * q;   // base n of this lane's 4 elements
    const size_t rowBase = (size_t)blockIdx.x * (2 * TRH);

    float yA[4], yB[4];  // y[r]: element (n = nq+r, batch = s) of tile A / B
    f32x4 accA, accB;

    // ---- stage both x tiles to LDS as bf16 (4 waves per tile, 32-col slices) ----
    {
        int tile  = wv >> 2;
        int slice = wv & 3;
        const float* xp = x + (rowBase + tile * TRH + s) * H + 32 * slice + q * 8;
        float4 v0 = *(const float4*)xp;
        float4 v1 = *(const float4*)(xp + 4);
        bf16x8 a;
        a[0] = f2bf(v0.x); a[1] = f2bf(v0.y); a[2] = f2bf(v0.z); a[3] = f2bf(v0.w);
        a[4] = f2bf(v1.x); a[5] = f2bf(v1.y); a[6] = f2bf(v1.z); a[7] = f2bf(v1.w);
        *(bf16x8*)&ab[tile][s * HBS + 32 * slice + q * 8] = a;
    }
    __syncthreads();

    // ---- in_proj GEMM, transposed: C[n][b] = (W_in^T) @ (x^T), both tiles ----
    {
        bf16x8 bfrA[4], bfrB[4];
        #pragma unroll
        for (int ks = 0; ks < 4; ++ks) {
            bfrA[ks] = *(const bf16x8*)&ab[0][s * HBS + ks * 32 + q * 8];
            bfrB[ks] = *(const bf16x8*)&ab[1][s * HBS + ks * 32 + q * 8];
        }
        accA = (f32x4){0.f, 0.f, 0.f, 0.f};
        accB = (f32x4){0.f, 0.f, 0.f, 0.f};
        #pragma unroll
        for (int ks = 0; ks < 4; ++ks) {
            bf16x8 a = *(const bf16x8*)&wt[(16 * wv + s) * H + ks * 32 + q * 8];
            accA = __builtin_amdgcn_mfma_f32_16x16x32_bf16(a, bfrA[ks], accA, 0, 0, 0);
            accB = __builtin_amdgcn_mfma_f32_16x16x32_bf16(a, bfrB[ks], accB, 0, 0, 0);
        }
        __syncthreads();   // all x-tile reads complete before y overwrites ab
        float4 bi4 = *(const float4*)&b_in[nq];
        yA[0] = accA[0] + bi4.x; yA[1] = accA[1] + bi4.y;
        yA[2] = accA[2] + bi4.z; yA[3] = accA[3] + bi4.w;
        yB[0] = accB[0] + bi4.x; yB[1] = accB[1] + bi4.y;
        yB[2] = accB[2] + bi4.z; yB[3] = accB[3] + bi4.w;
        uint loA = (uint)f2bf(yA[0]) | ((uint)f2bf(yA[1]) << 16);
        uint hiA = (uint)f2bf(yA[2]) | ((uint)f2bf(yA[3]) << 16);
        uint loB = (uint)f2bf(yB[0]) | ((uint)f2bf(yB[1]) << 16);
        uint hiB = (uint)f2bf(yB[2]) | ((uint)f2bf(yB[3]) << 16);
        *(uint2*)&ab[0][s * HBS + nq] = make_uint2(loA, hiA);
        *(uint2*)&ab[1][s * HBS + nq] = make_uint2(loB, hiB);
        __syncthreads();
    }

    // degree-4 Chebyshev-truncated minimax of e^v on [-1,1]
    const float cm[KT] = {1.00004478f, 0.99730768f, 0.49919676f, 0.17734736f, 0.04379392f};

    #pragma unroll 1
    for (int layer = 0; layer < NATT; ++layer) {
        const ushort* WT = wt + (size_t)(1 + layer) * 16384;

        // ---- phase A GEMM (transposed), both tiles share the weight A-frag ----
        bf16x8 bfrA[4], bfrB[4];
        #pragma unroll
        for (int ks = 0; ks < 4; ++ks) {
            bfrA[ks] = *(const bf16x8*)&ab[0][s * HBS + ks * 32 + q * 8];
            bfrB[ks] = *(const bf16x8*)&ab[1][s * HBS + ks * 32 + q * 8];
        }
        accA = (f32x4){0.f, 0.f, 0.f, 0.f};
        accB = (f32x4){0.f, 0.f, 0.f, 0.f};
        #pragma unroll
        for (int ks = 0; ks < 4; ++ks) {
            bf16x8 a = *(const bf16x8*)&WT[(16 * wv + s) * H + ks * 32 + q * 8];
            accA = __builtin_amdgcn_mfma_f32_16x16x32_bf16(a, bfrA[ks], accA, 0, 0, 0);
            accB = __builtin_amdgcn_mfma_f32_16x16x32_bf16(a, bfrB[ks], accB, 0, 0, 0);
        }
        float4 ba4 = *(const float4*)&b_att[layer * H + nq];
        float uA[4], uB[4];
        uA[0] = fast_tanh(accA[0] + ba4.x); uA[1] = fast_tanh(accA[1] + ba4.y);
        uA[2] = fast_tanh(accA[2] + ba4.z); uA[3] = fast_tanh(accA[3] + ba4.w);
        uB[0] = fast_tanh(accB[0] + ba4.x); uB[1] = fast_tanh(accB[1] + ba4.y);
        uB[2] = fast_tanh(accB[2] + ba4.z); uB[3] = fast_tanh(accB[3] + ba4.w);

        // ---- in-lane moments + wave reduce + exchange write, per tile ----
        #pragma unroll
        for (int tl = 0; tl < 2; ++tl) {
            const float* yy = tl ? yB : yA;
            const float* uu = tl ? uB : uA;
            float m0 = 0, m1 = 0, m2 = 0, m3 = 0, m4 = 0;
            float t1 = 0, t2 = 0, t3 = 0, t4 = 0;
            #pragma unroll
            for (int r = 0; r < 4; ++r) {
                float uv = uu[r], hh = yy[r];
                m0 += hh;
                float p = uv;
                m1 += p * hh; t1 += p;
                p *= uv; m2 += p * hh; t2 += p;
                p *= uv; m3 += p * hh; t3 += p;
                p *= uv; m4 += p * hh; t4 += p;
            }
            m0 = redq(m0); m1 = redq(m1); m2 = redq(m2); m3 = redq(m3); m4 = redq(m4);
            t1 = redq(t1); t2 = redq(t2); t3 = redq(t3); t4 = redq(t4);
            float* dst = &exm[tl][s * EXM_S + wv * 12];
            if (q == 0)      *(f32x4*)&dst[0] = (f32x4){m0, m1, m2, m3};
            else if (q == 1) *(f32x4*)&dst[4] = (f32x4){m4, t1, t2, t3};
            else if (q == 2) *(f32x4*)&dst[8] = (f32x4){t4, 0.f, 0.f, 0.f};
        }
        __syncthreads();

        // ---- cross-wave combine + Horner + residual + LN partial, per tile ----
        #pragma unroll
        for (int tl = 0; tl < 2; ++tl) {
            float* yy = tl ? yB : yA;
            const float* uu = tl ? uB : uA;
            const float* src = &exm[tl][s * EXM_S + 24 * q];
            f32x4 a0 = *(const f32x4*)&src[0];
            f32x4 a1 = *(const f32x4*)&src[4];
            f32x4 a2 = *(const f32x4*)&src[8];
            f32x4 b0 = *(const f32x4*)&src[12];
            f32x4 b1 = *(const f32x4*)&src[16];
            f32x4 b2 = *(const f32x4*)&src[20];
            a0 += b0; a1 += b1; a2 += b2;
            float S0  = redq(a0.x) * cm[0];
            float S1  = redq(a0.y) * cm[1];
            float S2  = redq(a0.z) * cm[2];
            float S3  = redq(a0.w) * cm[3];
            float S4  = redq(a1.x) * cm[4];
            float T1c = redq(a1.y) * cm[1];
            float T2c = redq(a1.z) * cm[2];
            float T3c = redq(a1.w) * cm[3];
            float T4c = redq(a2.x) * cm[4];
            float ls = 0.f, lq2 = 0.f;
            #pragma unroll
            for (int r = 0; r < 4; ++r) {
                float uv = uu[r];
                float num = fmaf(fmaf(fmaf(fmaf(S4, uv, S3), uv, S2), uv, S1), uv, S0);
                float den = fmaf(fmaf(fmaf(fmaf(T4c, uv, T3c), uv, T2c), uv, T1c), uv,
                                 128.f * 1.00004478f);   // c0 * T0
                float yv = yy[r] + num * __builtin_amdgcn_rcpf(den);
                yy[r] = yv;
                ls += yv; lq2 += yv * yv;
            }
            ls  = redq(ls);
            lq2 = redq(lq2);
            if (q == 0)
                *(float2*)&exl[tl][s * EXL_S + wv * 2] = make_float2(ls, lq2);
        }
        __syncthreads();

        // ---- LN combine + epilogue: normalize + refresh shared bf16 tiles ----
        float4 g4  = *(const float4*)&gamma[layer * H + nq];
        float4 be4 = *(const float4*)&beta [layer * H + nq];
        #pragma unroll
        for (int tl = 0; tl < 2; ++tl) {
            float* yy = tl ? yB : yA;
            f32x4 rd = *(const f32x4*)&exl[tl][s * EXL_S + 4 * q];  // copies 2q, 2q+1
            float sm  = redq(rd.x + rd.z);
            float sq2 = redq(rd.y + rd.w);
            float mu  = sm * (1.f / H);
            float var = sq2 * (1.f / H) - mu * mu;
            float inv = rsqrtf(var + EPS);
            float h0 = (yy[0] - mu) * inv * g4.x + be4.x;
            float h1 = (yy[1] - mu) * inv * g4.y + be4.y;
            float h2 = (yy[2] - mu) * inv * g4.z + be4.z;
            float h3 = (yy[3] - mu) * inv * g4.w + be4.w;
            yy[0] = h0; yy[1] = h1; yy[2] = h2; yy[3] = h3;
            uint lo = (uint)f2bf(h0) | ((uint)f2bf(h1) << 16);
            uint hi = (uint)f2bf(h2) | ((uint)f2bf(h3) << 16);
            *(uint2*)&ab[tl][s * HBS + nq] = make_uint2(lo, hi);
        }
        __syncthreads();
    }

    // ---- final proj: waves 0 and 4 compute 16 rows x NC (one tile each) ----
    if ((wv & 3) == 0) {
        int tile = wv >> 2;
        const ushort* WC = wt + 4 * 16384;
        f32x4 facc = (f32x4){0.f, 0.f, 0.f, 0.f};
        #pragma unroll
        for (int ks = 0; ks < 4; ++ks) {
            bf16x8 a = *(const bf16x8*)&ab[tile][s * HBS + ks * 32 + q * 8];
            bf16x8 b = *(const bf16x8*)&WC[s * H + ks * 32 + q * 8];
            facc = __builtin_amdgcn_mfma_f32_16x16x32_bf16(a, b, facc, 0, 0, 0);
        }
        if (s < NC) {
            float bc = b_c[s];
            #pragma unroll
            for (int r = 0; r < 4; ++r)
                out[(rowBase + tile * TRH + 4 * q + r) * NC + s] = facc[r] + bc;
        }
    }
}

extern "C" void kernel_launch(void* const* d_in, const int* in_sizes, int n_in,
                              void* d_out, int out_size, void* d_ws, size_t ws_size,
                              hipStream_t stream) {
    const float* x     = (const float*)d_in[0];
    const float* W_in  = (const float*)d_in[1];
    const float* b_in  = (const float*)d_in[2];
    const float* W_att = (const float*)d_in[3];
    const float* b_att = (const float*)d_in[4];
    const float* gamma = (const float*)d_in[5];
    const float* beta  = (const float*)d_in[6];
    const float* W_c   = (const float*)d_in[7];
    const float* b_c   = (const float*)d_in[8];
    float* out  = (float*)d_out;
    ushort* wt  = (ushort*)d_ws;    // 5 mats: 4*16384 + 2048 ushorts = 136 KiB

    hipLaunchKernelGGL(prep_weights, dim3(264), dim3(256), 0, stream,
                       W_in, W_att, W_c, wt);
    hipLaunchKernelGGL(simple_attention_kernel, dim3(B_TOT / (2 * TRH)), dim3(512), 0, stream,
                       x, b_in, b_att, gamma, beta, b_c, wt, out);
}